// Round 12
// baseline (891.497 us; speedup 1.0000x reference)
//
#include <hip/hip_runtime.h>
#include <hip/hip_bf16.h>
#include <math.h>

#define B 16
#define S 511
#define F 128
#define D 512
#define H 8
#define NB 6
#define DH 64
#define MLPD 2048
#define T 512
#define EPS 1e-5f

typedef unsigned short ushort;
typedef __attribute__((ext_vector_type(8))) short short8;
typedef __attribute__((ext_vector_type(4))) float floatx4;

__device__ __forceinline__ ushort f2bf(float f) {
    union { float f; unsigned u; } cv; cv.f = f;
    unsigned r = (cv.u + 0x7fff + ((cv.u >> 16) & 1)) >> 16;  // RNE
    return (ushort)r;
}

// Branch-free erf (Abramowitz-Stegun 7.1.26, |err| <= 1.5e-7) -> exact-GELU replacement
// for library erff (saves ~25 VALU instrs per call; gemm1 epilogue has 64 calls/thread).
__device__ __forceinline__ float fast_gelu(float x) {
    float z = fabsf(x) * 0.70710678118f;
    float t = 1.0f / (1.0f + 0.3275911f * z);
    float p = ((((1.061405429f * t - 1.453152027f) * t + 1.421413741f) * t
               - 0.284496736f) * t + 0.254829592f) * t;
    float erfv = 1.0f - p * __expf(-z * z);
    erfv = copysignf(erfv, x);
    return 0.5f * x * (1.0f + erfv);
}

// ---------------- cast src -> bf16 A-matrix for embed GEMM (t=0 rows zeroed) ----------------
__global__ void castsrc_kernel(const float* __restrict__ src, ushort* __restrict__ srcb) {
    int row = blockIdx.x;              // b*T + t
    int t = row & (T - 1), b = row >> 9;
    int tid = threadIdx.x;             // 128
    ushort v = 0;
    if (t > 0) v = f2bf(src[((size_t)b * S + (t - 1)) * F + tid]);
    srcb[(size_t)row * F + tid] = v;
}

// ---------------- generic transpose+cast: W [mat,K,N] fp32 -> Wt [mat,N,K] bf16 ----------------
__global__ void wtrans_kernel(const float* __restrict__ W,
                              ushort* __restrict__ Wt,
                              int K, int N) {
    int kb = blockIdx.x * 32, nb = blockIdx.y * 32, mat = blockIdx.z;
    __shared__ float tile[32][33];
    int tid = threadIdx.x; // 256
    int c = tid & 31, r0 = tid >> 5;
    const float* Wm = W + (size_t)mat * K * N;
    ushort* Wtm = Wt + (size_t)mat * K * N;
    #pragma unroll
    for (int l = 0; l < 4; ++l) {
        int r = r0 + l * 8;
        tile[r][c] = Wm[(size_t)(kb + r) * N + nb + c];
    }
    __syncthreads();
    #pragma unroll
    for (int l = 0; l < 4; ++l) {
        int r = r0 + l * 8;
        Wtm[(size_t)(nb + r) * K + kb + c] = f2bf(tile[c][r]);
    }
}

// ---------------- qkv weight transpose+cast ----------------
__global__ void wtransq_kernel(const float* __restrict__ Wq, const float* __restrict__ Wk,
                               const float* __restrict__ Wv,
                               ushort* __restrict__ WqT, ushort* __restrict__ WkT,
                               ushort* __restrict__ WvT) {
    int mat = blockIdx.x;          // 0..NB*H-1
    int which = blockIdx.y;        // 0,1,2
    const float* W = (which == 0 ? Wq : which == 1 ? Wk : Wv) + (size_t)mat * 4096;
    ushort* O = (which == 0 ? WqT : which == 1 ? WkT : WvT) + (size_t)mat * 4096;
    __shared__ float t[64][65];
    int tid = threadIdx.x;  // 256
    int r0 = tid >> 6, c = tid & 63;
    #pragma unroll
    for (int l = 0; l < 16; ++l) {
        int row = r0 * 16 + l;
        t[row][c] = W[row * 64 + c];
    }
    __syncthreads();
    #pragma unroll
    for (int l = 0; l < 16; ++l) {
        int row = r0 * 16 + l;
        O[row * 64 + c] = f2bf(t[c][row]);
    }
}

// ---------------- async global->LDS helper ----------------
__device__ __forceinline__ void gload_lds16(const ushort* g, ushort* l) {
    __builtin_amdgcn_global_load_lds((const __attribute__((address_space(1))) unsigned int*)g,
                                     (__attribute__((address_space(3))) unsigned int*)l,
                                     16, 0, 0);
}

// ---------------- embed GEMM: x = concat(cls, srcb@embWt^T)+emb_b+pe, fp32 out ----------------
__global__ __launch_bounds__(256) void embed_gemm(const ushort* __restrict__ A,
                                                  const ushort* __restrict__ Bt,
                                                  const float* __restrict__ emb_b,
                                                  const float* __restrict__ cls_tok,
                                                  float* __restrict__ x) {
    __shared__ ushort As[64 * 32];
    __shared__ ushort Bs[64 * 32];
    int tid = threadIdx.x;
    int lane = tid & 63;
    int w = __builtin_amdgcn_readfirstlane(tid >> 6);
    int quad = lane >> 4, l15 = lane & 15;
    int wr = (w >> 1) * 32, wc = (w & 1) * 32;
    int m0 = blockIdx.x * 64, n0 = blockIdx.y * 64;

    floatx4 acc[2][2];
    #pragma unroll
    for (int i = 0; i < 2; ++i)
        #pragma unroll
        for (int j = 0; j < 2; ++j) acc[i][j] = (floatx4)0.f;

    int lrow = lane >> 2;
    int lk = (lane & 3) * 8;
    const ushort* Ag = A + (size_t)(m0 + 16 * w + lrow) * F + lk;
    const ushort* Bg = Bt + (size_t)(n0 + 16 * w + lrow) * F + lk;
    ushort* AsW = &As[16 * w * 32];
    ushort* BsW = &Bs[16 * w * 32];
    int fa = l15 * 32 + quad * 8;

    for (int kt = 0; kt < F; kt += 32) {
        gload_lds16(Ag + kt, AsW);
        gload_lds16(Bg + kt, BsW);
        __syncthreads();
        short8 af[2], bf[2];
        #pragma unroll
        for (int i = 0; i < 2; ++i) af[i] = *(const short8*)&As[(wr + 16 * i) * 32 + fa];
        #pragma unroll
        for (int j = 0; j < 2; ++j) bf[j] = *(const short8*)&Bs[(wc + 16 * j) * 32 + fa];
        #pragma unroll
        for (int i = 0; i < 2; ++i)
            #pragma unroll
            for (int j = 0; j < 2; ++j)
                acc[i][j] = __builtin_amdgcn_mfma_f32_16x16x32_bf16(af[i], bf[j], acc[i][j], 0, 0, 0);
        __syncthreads();
    }

    const float LOG1E4 = 9.210340371976184f;
    int rbase = (lane >> 4) * 4;
    int cidx = lane & 15;
    #pragma unroll
    for (int j = 0; j < 2; ++j) {
        int gc = n0 + wc + 16 * j + cidx;
        float je = (float)(gc & ~1);
        float freq = expf(-(je / (float)D) * LOG1E4);
        float ebv = emb_b[gc];
        float clsv = cls_tok[gc];
        bool odd = (gc & 1);
        #pragma unroll
        for (int i = 0; i < 2; ++i) {
            int gr = m0 + wr + 16 * i + rbase;
            #pragma unroll
            for (int reg = 0; reg < 4; ++reg) {
                int row = gr + reg;
                int t = row & (T - 1);
                float ang = (float)t * freq;
                float pe = odd ? cosf(ang) : sinf(ang);
                float val = (t == 0) ? (clsv + pe) : (acc[i][j][reg] + ebv + pe);
                x[(size_t)row * D + gc] = val;
            }
        }
    }
}

// ---------------- layernorm -> bf16: one wave per row, shuffle-only ----------------
__global__ __launch_bounds__(256) void ln_kernel(const float* __restrict__ xin,
                                                 const float* __restrict__ g,
                                                 const float* __restrict__ bb,
                                                 ushort* __restrict__ out) {
    int lane = threadIdx.x & 63;
    int row = blockIdx.x * 4 + (threadIdx.x >> 6);
    const float* xr = xin + (size_t)row * D + lane * 8;
    float4 a0 = *(const float4*)xr;
    float4 a1 = *(const float4*)(xr + 4);
    float s = a0.x + a0.y + a0.z + a0.w + a1.x + a1.y + a1.z + a1.w;
    #pragma unroll
    for (int off = 1; off < 64; off <<= 1) s += __shfl_xor(s, off);
    float mean = s * (1.0f / (float)D);
    float d0 = a0.x - mean, d1 = a0.y - mean, d2 = a0.z - mean, d3 = a0.w - mean;
    float d4 = a1.x - mean, d5 = a1.y - mean, d6 = a1.z - mean, d7 = a1.w - mean;
    float sq = d0*d0 + d1*d1 + d2*d2 + d3*d3 + d4*d4 + d5*d5 + d6*d6 + d7*d7;
    #pragma unroll
    for (int off = 1; off < 64; off <<= 1) sq += __shfl_xor(sq, off);
    float rstd = rsqrtf(sq * (1.0f / (float)D) + EPS);
    const float* gp = g + lane * 8;
    const float* bp = bb + lane * 8;
    float4 g0 = *(const float4*)gp, g1 = *(const float4*)(gp + 4);
    float4 b0 = *(const float4*)bp, b1 = *(const float4*)(bp + 4);
    short8 o;
    o[0] = (short)f2bf(d0 * rstd * g0.x + b0.x);
    o[1] = (short)f2bf(d1 * rstd * g0.y + b0.y);
    o[2] = (short)f2bf(d2 * rstd * g0.z + b0.z);
    o[3] = (short)f2bf(d3 * rstd * g0.w + b0.w);
    o[4] = (short)f2bf(d4 * rstd * g1.x + b1.x);
    o[5] = (short)f2bf(d5 * rstd * g1.y + b1.y);
    o[6] = (short)f2bf(d6 * rstd * g1.z + b1.z);
    o[7] = (short)f2bf(d7 * rstd * g1.w + b1.w);
    *(short8*)(out + (size_t)row * D + lane * 8) = o;
}

// ---------------- fused: x += p0 (deferred W2 partial), then LN -> bf16 ----------------
__global__ __launch_bounds__(256) void ln_fuse_kernel(float* __restrict__ x,
                                                      const float* __restrict__ p0,
                                                      const float* __restrict__ g,
                                                      const float* __restrict__ bb,
                                                      ushort* __restrict__ out) {
    int lane = threadIdx.x & 63;
    int row = blockIdx.x * 4 + (threadIdx.x >> 6);
    size_t base = (size_t)row * D + lane * 8;
    float* xr = x + base;
    float4 a0 = *(const float4*)xr;
    float4 a1 = *(const float4*)(xr + 4);
    float4 q0 = *(const float4*)(p0 + base);
    float4 q1 = *(const float4*)(p0 + base + 4);
    a0.x += q0.x; a0.y += q0.y; a0.z += q0.z; a0.w += q0.w;
    a1.x += q1.x; a1.y += q1.y; a1.z += q1.z; a1.w += q1.w;
    *(float4*)xr = a0;
    *(float4*)(xr + 4) = a1;
    float s = a0.x + a0.y + a0.z + a0.w + a1.x + a1.y + a1.z + a1.w;
    #pragma unroll
    for (int off = 1; off < 64; off <<= 1) s += __shfl_xor(s, off);
    float mean = s * (1.0f / (float)D);
    float d0 = a0.x - mean, d1 = a0.y - mean, d2 = a0.z - mean, d3 = a0.w - mean;
    float d4 = a1.x - mean, d5 = a1.y - mean, d6 = a1.z - mean, d7 = a1.w - mean;
    float sq = d0*d0 + d1*d1 + d2*d2 + d3*d3 + d4*d4 + d5*d5 + d6*d6 + d7*d7;
    #pragma unroll
    for (int off = 1; off < 64; off <<= 1) sq += __shfl_xor(sq, off);
    float rstd = rsqrtf(sq * (1.0f / (float)D) + EPS);
    const float* gp = g + lane * 8;
    const float* bp = bb + lane * 8;
    float4 g0 = *(const float4*)gp, g1 = *(const float4*)(gp + 4);
    float4 b0 = *(const float4*)bp, b1 = *(const float4*)(bp + 4);
    short8 o;
    o[0] = (short)f2bf(d0 * rstd * g0.x + b0.x);
    o[1] = (short)f2bf(d1 * rstd * g0.y + b0.y);
    o[2] = (short)f2bf(d2 * rstd * g0.z + b0.z);
    o[3] = (short)f2bf(d3 * rstd * g0.w + b0.w);
    o[4] = (short)f2bf(d4 * rstd * g1.x + b1.x);
    o[5] = (short)f2bf(d5 * rstd * g1.y + b1.y);
    o[6] = (short)f2bf(d6 * rstd * g1.z + b1.z);
    o[7] = (short)f2bf(d7 * rstd * g1.w + b1.w);
    *(short8*)(out + (size_t)row * D + lane * 8) = o;
}

// ---------------- QKV: per-head MFMA GEMM ----------------
__global__ __launch_bounds__(256) void qkv_kernel(
        const ushort* __restrict__ hb,
        const ushort* __restrict__ WqT, const float* __restrict__ bq,
        const ushort* __restrict__ WkT, const float* __restrict__ bk,
        const ushort* __restrict__ WvT, const float* __restrict__ bv,
        ushort* __restrict__ qo, ushort* __restrict__ ko, ushort* __restrict__ vTo) {
    int m0 = blockIdx.x * 128;
    int hh = blockIdx.y;
    int tid = threadIdx.x;
    int lane = tid & 63;
    int w = __builtin_amdgcn_readfirstlane(tid >> 6);
    int quad = lane >> 4, l15 = lane & 15;

    short8 af[2][2];
    #pragma unroll
    for (int mt = 0; mt < 2; ++mt) {
        const ushort* ab = hb + (size_t)(m0 + w * 32 + mt * 16 + l15) * D + hh * DH + quad * 8;
        af[mt][0] = *(const short8*)(ab);
        af[mt][1] = *(const short8*)(ab + 32);
    }

    floatx4 acc[3][2][4];
    #pragma unroll
    for (int xo = 0; xo < 3; ++xo)
        #pragma unroll
        for (int mt = 0; mt < 2; ++mt)
            #pragma unroll
            for (int nt = 0; nt < 4; ++nt) acc[xo][mt][nt] = (floatx4)0.f;

    #pragma unroll
    for (int xo = 0; xo < 3; ++xo) {
        const ushort* WT = (xo == 0 ? WqT : xo == 1 ? WkT : WvT) + (size_t)hh * 4096;
        #pragma unroll
        for (int nt = 0; nt < 4; ++nt) {
            const ushort* wb = WT + (size_t)(nt * 16 + l15) * 64 + quad * 8;
            short8 bf0 = *(const short8*)(wb);
            short8 bf1 = *(const short8*)(wb + 32);
            #pragma unroll
            for (int mt = 0; mt < 2; ++mt) {
                acc[xo][mt][nt] = __builtin_amdgcn_mfma_f32_16x16x32_bf16(af[mt][0], bf0, acc[xo][mt][nt], 0, 0, 0);
                acc[xo][mt][nt] = __builtin_amdgcn_mfma_f32_16x16x32_bf16(af[mt][1], bf1, acc[xo][mt][nt], 0, 0, 0);
            }
        }
    }

    int bb = m0 >> 9;
    int bh = bb * H + hh;
    #pragma unroll
    for (int mt = 0; mt < 2; ++mt) {
        int trow = m0 + w * 32 + mt * 16 + quad * 4;
        int tt = trow & (T - 1);
        #pragma unroll
        for (int nt = 0; nt < 4; ++nt) {
            int col = nt * 16 + l15;
            float bqv = bq[hh * DH + col];
            float bkv = bk[hh * DH + col];
            float bvv = bv[hh * DH + col];
            #pragma unroll
            for (int reg = 0; reg < 4; ++reg) {
                qo[((size_t)bh * T + tt + reg) * DH + col] = f2bf(acc[0][mt][nt][reg] + bqv);
                ko[((size_t)bh * T + tt + reg) * DH + col] = f2bf(acc[1][mt][nt][reg] + bkv);
                vTo[((size_t)bh * DH + col) * T + tt + reg] = f2bf(acc[2][mt][nt][reg] + bvv);
            }
        }
    }
}

// ---------------- MFMA flash attention, max-free softmax + deferred normalization ----------------
#define PSTRIDE 88
__global__ __launch_bounds__(256) void attn_kernel(const ushort* __restrict__ q,
                                                   const ushort* __restrict__ k,
                                                   const ushort* __restrict__ vT,
                                                   float* __restrict__ x) {
    int bh = blockIdx.x;
    int qt = blockIdx.y;
    int b = bh >> 3, hh = bh & 7;
    int tid = threadIdx.x;
    int lane = tid & 63;
    int w = __builtin_amdgcn_readfirstlane(tid >> 6);   // 0..3
    int quad = lane >> 4, l15 = lane & 15;

    __shared__ __align__(16) ushort smem[22016];   // 44032 B
    ushort* Pw = smem + 16384 + w * (16 * PSTRIDE);

    const ushort* qbase = q + ((size_t)bh * T + qt * 64 + w * 16 + l15) * DH + quad * 8;
    short8 Qf0 = *(const short8*)(qbase);
    short8 Qf1 = *(const short8*)(qbase + 32);

    const ushort* kbase = k + (size_t)bh * T * DH;
    const ushort* vbase = vT + (size_t)bh * DH * T;

    int srow = lane >> 2;
    int scol = (lane & 3) * 8;
    const ushort* kg = kbase + (size_t)(w * 16 + srow) * DH + scol;
    const ushort* vg = vbase + (size_t)(w * 16 + srow) * T + scol;
    ushort* ldsK = smem + w * 16 * 32;
    ushort* ldsV = smem + 8192 + w * 16 * 32;

    float l_i[4] = {0.f, 0.f, 0.f, 0.f};
    floatx4 O[4];
    #pragma unroll
    for (int j = 0; j < 4; ++j) O[j] = (floatx4)0.f;

    gload_lds16(kg, ldsK);
    gload_lds16(kg + 32, ldsK + 2048);
    gload_lds16(vg, ldsV);
    gload_lds16(vg + 32, ldsV + 2048);
    __syncthreads();

    for (int kt = 0; kt < T / 64; ++kt) {
        int cur = kt & 1;
        if (kt < T / 64 - 1) {
            int nb = cur ^ 1;
            const ushort* kgn = kg + (size_t)(kt + 1) * 64 * DH;
            const ushort* vgn = vg + (kt + 1) * 64;
            gload_lds16(kgn, ldsK + nb * 4096);
            gload_lds16(kgn + 32, ldsK + nb * 4096 + 2048);
            gload_lds16(vgn, ldsV + nb * 4096);
            gload_lds16(vgn + 32, ldsV + nb * 4096 + 2048);
        }
        const ushort* Kc = smem + cur * 4096;
        const ushort* Vc = smem + 8192 + cur * 4096;

        floatx4 sc[4];
        #pragma unroll
        for (int j = 0; j < 4; ++j) {
            int ro = (j * 16 + l15) * 32 + quad * 8;
            short8 kf0 = *(const short8*)&Kc[ro];
            short8 kf1 = *(const short8*)&Kc[2048 + ro];
            floatx4 s4 = (floatx4)0.f;
            s4 = __builtin_amdgcn_mfma_f32_16x16x32_bf16(Qf0, kf0, s4, 0, 0, 0);
            s4 = __builtin_amdgcn_mfma_f32_16x16x32_bf16(Qf1, kf1, s4, 0, 0, 0);
            sc[j] = s4;
        }
        #pragma unroll
        for (int j = 0; j < 4; ++j) {
            #pragma unroll
            for (int r = 0; r < 4; ++r) {
                float p = __expf(sc[j][r] * 0.125f);
                ushort pb = f2bf(p);
                union { unsigned u; float f; } cv; cv.u = ((unsigned)pb) << 16;
                l_i[r] += cv.f;
                Pw[(quad * 4 + r) * PSTRIDE + j * 16 + l15] = pb;
            }
        }

        short8 af0 = *(const short8*)&Pw[l15 * PSTRIDE + quad * 8];
        short8 af1 = *(const short8*)&Pw[l15 * PSTRIDE + 32 + quad * 8];
        #pragma unroll
        for (int j = 0; j < 4; ++j) {
            int ro = (j * 16 + l15) * 32 + quad * 8;
            short8 vf0 = *(const short8*)&Vc[ro];
            short8 vf1 = *(const short8*)&Vc[2048 + ro];
            O[j] = __builtin_amdgcn_mfma_f32_16x16x32_bf16(af0, vf0, O[j], 0, 0, 0);
            O[j] = __builtin_amdgcn_mfma_f32_16x16x32_bf16(af1, vf1, O[j], 0, 0, 0);
        }
        __syncthreads();
    }

    #pragma unroll
    for (int r = 0; r < 4; ++r) {
        l_i[r] += __shfl_xor(l_i[r], 1);
        l_i[r] += __shfl_xor(l_i[r], 2);
        l_i[r] += __shfl_xor(l_i[r], 4);
        l_i[r] += __shfl_xor(l_i[r], 8);
    }

    float* Ow = (float*)smem + w * 16 * 68;
    #pragma unroll
    for (int r = 0; r < 4; ++r) {
        float rl = 1.0f / l_i[r];
        #pragma unroll
        for (int j = 0; j < 4; ++j)
            Ow[(quad * 4 + r) * 68 + j * 16 + l15] = O[j][r] * rl;
    }
    __syncthreads();
    int r4 = lane >> 4;
    int c16 = lane & 15;
    #pragma unroll
    for (int i = 0; i < 4; ++i) {
        int lrow = i * 4 + r4;
        float4 o = *(const float4*)&Ow[lrow * 68 + c16 * 4];
        int grow = qt * 64 + w * 16 + lrow;
        float* xp = &x[((size_t)(b * T) + grow) * D + hh * DH + c16 * 4];
        float4 xv = *(const float4*)xp;
        xv.x += o.x; xv.y += o.y; xv.z += o.z; xv.w += o.w;
        *(float4*)xp = xv;
    }
}

// ---------------- gemm1: C(bf16) = gelu(A@Bt^T + bias), tile 128x128, BK=64 ----------------
__global__ __launch_bounds__(256) void mfma_gemm_gelu(const ushort* __restrict__ A,
                                                      const ushort* __restrict__ Bt,
                                                      const float* __restrict__ bias,
                                                      ushort* __restrict__ C,
                                                      int M, int N, int K) {
    __shared__ ushort As0[128 * 32];
    __shared__ ushort As1[128 * 32];
    __shared__ ushort Bs0[128 * 32];
    __shared__ ushort Bs1[128 * 32];
    int tid = threadIdx.x;
    int lane = tid & 63;
    int w = __builtin_amdgcn_readfirstlane(tid >> 6);
    int wr = (w >> 1) * 64, wc = (w & 1) * 64;
    int m0 = blockIdx.x * 128, n0 = blockIdx.y * 128;

    floatx4 acc[4][4];
    #pragma unroll
    for (int i = 0; i < 4; ++i)
        #pragma unroll
        for (int j = 0; j < 4; ++j) acc[i][j] = (floatx4)0.f;

    int lrow = lane >> 2;
    int lk = (lane & 3) * 8;
    const ushort* Ag = A + (size_t)(m0 + 32 * w + lrow) * K + lk;
    const ushort* Bg = Bt + (size_t)(n0 + 32 * w + lrow) * K + lk;
    ushort* As0W = &As0[(32 * w) * 32];
    ushort* As1W = &As1[(32 * w) * 32];
    ushort* Bs0W = &Bs0[(32 * w) * 32];
    ushort* Bs1W = &Bs1[(32 * w) * 32];
    int fa = (lane & 15) * 32 + (lane >> 4) * 8;

    for (int kt = 0; kt < K; kt += 64) {
        gload_lds16(Ag + kt, As0W);
        gload_lds16(Ag + kt + (size_t)16 * K, As0W + 16 * 32);
        gload_lds16(Ag + kt + 32, As1W);
        gload_lds16(Ag + kt + 32 + (size_t)16 * K, As1W + 16 * 32);
        gload_lds16(Bg + kt, Bs0W);
        gload_lds16(Bg + kt + (size_t)16 * K, Bs0W + 16 * 32);
        gload_lds16(Bg + kt + 32, Bs1W);
        gload_lds16(Bg + kt + 32 + (size_t)16 * K, Bs1W + 16 * 32);
        __syncthreads();
        short8 af0[4], af1[4], bf0[4], bf1[4];
        #pragma unroll
        for (int i = 0; i < 4; ++i) {
            af0[i] = *(const short8*)&As0[(wr + 16 * i) * 32 + fa];
            af1[i] = *(const short8*)&As1[(wr + 16 * i) * 32 + fa];
        }
        #pragma unroll
        for (int j = 0; j < 4; ++j) {
            bf0[j] = *(const short8*)&Bs0[(wc + 16 * j) * 32 + fa];
            bf1[j] = *(const short8*)&Bs1[(wc + 16 * j) * 32 + fa];
        }
        #pragma unroll
        for (int i = 0; i < 4; ++i)
            #pragma unroll
            for (int j = 0; j < 4; ++j) {
                acc[i][j] = __builtin_amdgcn_mfma_f32_16x16x32_bf16(af0[i], bf0[j], acc[i][j], 0, 0, 0);
                acc[i][j] = __builtin_amdgcn_mfma_f32_16x16x32_bf16(af1[i], bf1[j], acc[i][j], 0, 0, 0);
            }
        __syncthreads();
    }

    int rbase = (lane >> 4) * 4;
    int cidx = lane & 15;
    #pragma unroll
    for (int i = 0; i < 4; ++i) {
        #pragma unroll
        for (int j = 0; j < 4; ++j) {
            int gc = n0 + wc + 16 * j + cidx;
            float bv = bias[gc];
            int gr = m0 + wr + 16 * i + rbase;
            #pragma unroll
            for (int reg = 0; reg < 4; ++reg) {
                float val = fast_gelu(acc[i][j][reg] + bv);
                C[(size_t)(gr + reg) * N + gc] = f2bf(val);
            }
        }
    }
}

// ---------------- gemm2: P(fp32) = A@Bt^T + bias, tile 128x64, full K ----------------
// N-split (not K-split): grid (M/128, N/64) = 512 blocks, LDS 24KB -> high occupancy,
// writes a SINGLE 16MB fp32 partial (half the traffic of the K-split version).
__global__ __launch_bounds__(256) void mfma_gemm_p(const ushort* __restrict__ A,
                                                   const ushort* __restrict__ Bt,
                                                   const float* __restrict__ bias,
                                                   float* __restrict__ C,
                                                   int M, int N, int K) {
    __shared__ ushort As0[128 * 32];
    __shared__ ushort As1[128 * 32];
    __shared__ ushort Bs0[64 * 32];
    __shared__ ushort Bs1[64 * 32];
    int tid = threadIdx.x;
    int lane = tid & 63;
    int w = __builtin_amdgcn_readfirstlane(tid >> 6);
    int wr = (w >> 1) * 64, wc = (w & 1) * 32;
    int m0 = blockIdx.x * 128, n0 = blockIdx.y * 64;

    floatx4 acc[4][2];
    #pragma unroll
    for (int i = 0; i < 4; ++i)
        #pragma unroll
        for (int j = 0; j < 2; ++j) acc[i][j] = (floatx4)0.f;

    int lrow = lane >> 2;
    int lk = (lane & 3) * 8;
    const ushort* Ag = A + (size_t)(m0 + 32 * w + lrow) * K + lk;
    const ushort* Bg = Bt + (size_t)(n0 + 16 * w + lrow) * K + lk;
    ushort* As0W = &As0[(32 * w) * 32];
    ushort* As1W = &As1[(32 * w) * 32];
    ushort* Bs0W = &Bs0[(16 * w) * 32];
    ushort* Bs1W = &Bs1[(16 * w) * 32];
    int fa = (lane & 15) * 32 + (lane >> 4) * 8;

    for (int kt = 0; kt < K; kt += 64) {
        gload_lds16(Ag + kt, As0W);
        gload_lds16(Ag + kt + (size_t)16 * K, As0W + 16 * 32);
        gload_lds16(Ag + kt + 32, As1W);
        gload_lds16(Ag + kt + 32 + (size_t)16 * K, As1W + 16 * 32);
        gload_lds16(Bg + kt, Bs0W);
        gload_lds16(Bg + kt + 32, Bs1W);
        __syncthreads();
        short8 af0[4], af1[4], bf0[2], bf1[2];
        #pragma unroll
        for (int i = 0; i < 4; ++i) {
            af0[i] = *(const short8*)&As0[(wr + 16 * i) * 32 + fa];
            af1[i] = *(const short8*)&As1[(wr + 16 * i) * 32 + fa];
        }
        #pragma unroll
        for (int j = 0; j < 2; ++j) {
            bf0[j] = *(const short8*)&Bs0[(wc + 16 * j) * 32 + fa];
            bf1[j] = *(const short8*)&Bs1[(wc + 16 * j) * 32 + fa];
        }
        #pragma unroll
        for (int i = 0; i < 4; ++i)
            #pragma unroll
            for (int j = 0; j < 2; ++j) {
                acc[i][j] = __builtin_amdgcn_mfma_f32_16x16x32_bf16(af0[i], bf0[j], acc[i][j], 0, 0, 0);
                acc[i][j] = __builtin_amdgcn_mfma_f32_16x16x32_bf16(af1[i], bf1[j], acc[i][j], 0, 0, 0);
            }
        __syncthreads();
    }

    int rbase = (lane >> 4) * 4;
    int cidx = lane & 15;
    #pragma unroll
    for (int i = 0; i < 4; ++i) {
        #pragma unroll
        for (int j = 0; j < 2; ++j) {
            int gc = n0 + wc + 16 * j + cidx;
            float bv = bias[gc];
            int gr = m0 + wr + 16 * i + rbase;
            #pragma unroll
            for (int reg = 0; reg < 4; ++reg) {
                C[(size_t)(gr + reg) * N + gc] = acc[i][j][reg] + bv;
            }
        }
    }
}

// ---------------- head: out[b] = sigmoid((x[b,0]+p0[b,0]) . head_W + head_b) ----------------
__global__ void head_kernel(const float* __restrict__ x,
                            const float* __restrict__ p0,
                            const float* __restrict__ hw,
                            const float* __restrict__ hb,
                            float* __restrict__ out) {
    int b = blockIdx.x;
    int tid = threadIdx.x; // 512
    size_t idx = (size_t)b * T * D + tid;
    float s = (x[idx] + p0[idx]) * hw[tid];
    #pragma unroll
    for (int off = 32; off > 0; off >>= 1) s += __shfl_down(s, off, 64);
    __shared__ float red[8];
    if ((tid & 63) == 0) red[tid >> 6] = s;
    __syncthreads();
    if (tid == 0) {
        float t = 0.f;
        #pragma unroll
        for (int i = 0; i < 8; ++i) t += red[i];
        out[b] = 1.0f / (1.0f + __expf(-(t + hb[0])));
    }
}

extern "C" void kernel_launch(void* const* d_in, const int* in_sizes, int n_in,
                              void* d_out, int out_size, void* d_ws, size_t ws_size,
                              hipStream_t stream) {
    const float* src     = (const float*)d_in[0];
    const float* emb_W   = (const float*)d_in[1];
    const float* emb_b   = (const float*)d_in[2];
    const float* cls_tok = (const float*)d_in[3];
    const float* ln1_g   = (const float*)d_in[4];
    const float* ln1_b   = (const float*)d_in[5];
    const float* Wq      = (const float*)d_in[6];
    const float* bq      = (const float*)d_in[7];
    const float* Wk      = (const float*)d_in[8];
    const float* bk      = (const float*)d_in[9];
    const float* Wv      = (const float*)d_in[10];
    const float* bv      = (const float*)d_in[11];
    const float* ln2_g   = (const float*)d_in[12];
    const float* ln2_b   = (const float*)d_in[13];
    const float* W1      = (const float*)d_in[14];
    const float* b1      = (const float*)d_in[15];
    const float* W2      = (const float*)d_in[16];
    const float* b2      = (const float*)d_in[17];
    const float* head_W  = (const float*)d_in[18];
    const float* head_b  = (const float*)d_in[19];

    const size_t NTOK = (size_t)B * T;          // 8192
    char* wsb = (char*)d_ws;
    float*  x    = (float*)wsb;      wsb += NTOK * D * 4;
    float*  p0   = (float*)wsb;      wsb += NTOK * D * 4;      // single W2 partial (16MB)
    ushort* hbuf = (ushort*)wsb;     wsb += NTOK * D * 2;
    ushort* q    = (ushort*)wsb;     wsb += NTOK * D * 2;
    ushort* k    = (ushort*)wsb;     wsb += NTOK * D * 2;
    ushort* vT   = (ushort*)wsb;     wsb += NTOK * D * 2;
    ushort* u    = (ushort*)wsb;     wsb += NTOK * MLPD * 2;
    ushort* W1t  = (ushort*)wsb;     wsb += (size_t)NB * D * MLPD * 2;
    ushort* W2t  = (ushort*)wsb;     wsb += (size_t)NB * D * MLPD * 2;
    ushort* WqT  = (ushort*)wsb;     wsb += (size_t)NB * H * DH * DH * 2;
    ushort* WkT  = (ushort*)wsb;     wsb += (size_t)NB * H * DH * DH * 2;
    ushort* WvT  = (ushort*)wsb;     wsb += (size_t)NB * H * DH * DH * 2;
    ushort* srcb = (ushort*)wsb;     wsb += NTOK * F * 2;
    ushort* embWt= (ushort*)wsb;     wsb += (size_t)F * D * 2;

    // weight / input prep (every launch)
    wtrans_kernel<<<dim3(D / 32, MLPD / 32, NB), 256, 0, stream>>>(W1, W1t, D, MLPD);
    wtrans_kernel<<<dim3(MLPD / 32, D / 32, NB), 256, 0, stream>>>(W2, W2t, MLPD, D);
    wtransq_kernel<<<dim3(NB * H, 3), 256, 0, stream>>>(Wq, Wk, Wv, WqT, WkT, WvT);
    wtrans_kernel<<<dim3(F / 32, D / 32, 1), 256, 0, stream>>>(emb_W, embWt, F, D);
    castsrc_kernel<<<B * T, F, 0, stream>>>(src, srcb);

    embed_gemm<<<dim3(B * T / 64, D / 64), 256, 0, stream>>>(srcb, embWt, emb_b, cls_tok, x);

    for (int i = 0; i < NB; ++i) {
        if (i == 0)
            ln_kernel<<<B * T / 4, 256, 0, stream>>>(x, ln1_g, ln1_b, hbuf);
        else
            ln_fuse_kernel<<<B * T / 4, 256, 0, stream>>>(x, p0,
                ln1_g + i * D, ln1_b + i * D, hbuf);
        qkv_kernel<<<dim3(B * T / 128, H), 256, 0, stream>>>(hbuf,
            WqT + (size_t)i * H * DH * DH, bq + (size_t)i * H * DH,
            WkT + (size_t)i * H * DH * DH, bk + (size_t)i * H * DH,
            WvT + (size_t)i * H * DH * DH, bv + (size_t)i * H * DH,
            q, k, vT);
        attn_kernel<<<dim3(B * H, T / 64), 256, 0, stream>>>(q, k, vT, x);
        ln_kernel<<<B * T / 4, 256, 0, stream>>>(x, ln2_g + i * D, ln2_b + i * D, hbuf);
        mfma_gemm_gelu<<<dim3(B * T / 128, MLPD / 128), 256, 0, stream>>>(
            hbuf, W1t + (size_t)i * D * MLPD, b1 + (size_t)i * MLPD, u, B * T, MLPD, D);
        mfma_gemm_p<<<dim3(B * T / 128, D / 64), 256, 0, stream>>>(
            u, W2t + (size_t)i * MLPD * D, b2 + (size_t)i * D, p0, B * T, D, MLPD);
    }

    head_kernel<<<B, 512, 0, stream>>>(x, p0, head_W, head_b, (float*)d_out);
}

// Round 13
// 870.254 us; speedup vs baseline: 1.0244x; 1.0244x over previous
//
#include <hip/hip_runtime.h>
#include <hip/hip_bf16.h>
#include <math.h>

#define B 16
#define S 511
#define F 128
#define D 512
#define H 8
#define NB 6
#define DH 64
#define MLPD 2048
#define T 512
#define EPS 1e-5f

typedef unsigned short ushort;
typedef __attribute__((ext_vector_type(8))) short short8;
typedef __attribute__((ext_vector_type(4))) float floatx4;

__device__ __forceinline__ ushort f2bf(float f) {
    union { float f; unsigned u; } cv; cv.f = f;
    unsigned r = (cv.u + 0x7fff + ((cv.u >> 16) & 1)) >> 16;  // RNE
    return (ushort)r;
}

// Branch-free erf (Abramowitz-Stegun 7.1.26, |err| <= 1.5e-7)
__device__ __forceinline__ float fast_gelu(float x) {
    float z = fabsf(x) * 0.70710678118f;
    float t = 1.0f / (1.0f + 0.3275911f * z);
    float p = ((((1.061405429f * t - 1.453152027f) * t + 1.421413741f) * t
               - 0.284496736f) * t + 0.254829592f) * t;
    float erfv = 1.0f - p * __expf(-z * z);
    erfv = copysignf(erfv, x);
    return 0.5f * x * (1.0f + erfv);
}

// ---------------- cast src -> bf16 A-matrix for embed GEMM (t=0 rows zeroed) ----------------
__global__ void castsrc_kernel(const float* __restrict__ src, ushort* __restrict__ srcb) {
    int row = blockIdx.x;              // b*T + t
    int t = row & (T - 1), b = row >> 9;
    int tid = threadIdx.x;             // 128
    ushort v = 0;
    if (t > 0) v = f2bf(src[((size_t)b * S + (t - 1)) * F + tid]);
    srcb[(size_t)row * F + tid] = v;
}

// ---------------- generic transpose+cast: W [mat,K,N] fp32 -> Wt [mat,N,K] bf16 ----------------
__global__ void wtrans_kernel(const float* __restrict__ W,
                              ushort* __restrict__ Wt,
                              int K, int N) {
    int kb = blockIdx.x * 32, nb = blockIdx.y * 32, mat = blockIdx.z;
    __shared__ float tile[32][33];
    int tid = threadIdx.x; // 256
    int c = tid & 31, r0 = tid >> 5;
    const float* Wm = W + (size_t)mat * K * N;
    ushort* Wtm = Wt + (size_t)mat * K * N;
    #pragma unroll
    for (int l = 0; l < 4; ++l) {
        int r = r0 + l * 8;
        tile[r][c] = Wm[(size_t)(kb + r) * N + nb + c];
    }
    __syncthreads();
    #pragma unroll
    for (int l = 0; l < 4; ++l) {
        int r = r0 + l * 8;
        Wtm[(size_t)(nb + r) * K + kb + c] = f2bf(tile[c][r]);
    }
}

// ---------------- qkv weight transpose+cast ----------------
__global__ void wtransq_kernel(const float* __restrict__ Wq, const float* __restrict__ Wk,
                               const float* __restrict__ Wv,
                               ushort* __restrict__ WqT, ushort* __restrict__ WkT,
                               ushort* __restrict__ WvT) {
    int mat = blockIdx.x;          // 0..NB*H-1
    int which = blockIdx.y;        // 0,1,2
    const float* W = (which == 0 ? Wq : which == 1 ? Wk : Wv) + (size_t)mat * 4096;
    ushort* O = (which == 0 ? WqT : which == 1 ? WkT : WvT) + (size_t)mat * 4096;
    __shared__ float t[64][65];
    int tid = threadIdx.x;  // 256
    int r0 = tid >> 6, c = tid & 63;
    #pragma unroll
    for (int l = 0; l < 16; ++l) {
        int row = r0 * 16 + l;
        t[row][c] = W[row * 64 + c];
    }
    __syncthreads();
    #pragma unroll
    for (int l = 0; l < 16; ++l) {
        int row = r0 * 16 + l;
        O[row * 64 + c] = f2bf(t[c][row]);
    }
}

// ---------------- async global->LDS helper ----------------
__device__ __forceinline__ void gload_lds16(const ushort* g, ushort* l) {
    __builtin_amdgcn_global_load_lds((const __attribute__((address_space(1))) unsigned int*)g,
                                     (__attribute__((address_space(3))) unsigned int*)l,
                                     16, 0, 0);
}

// ---------------- embed GEMM: x = concat(cls, srcb@embWt^T)+emb_b+pe, fp32 out ----------------
__global__ __launch_bounds__(256) void embed_gemm(const ushort* __restrict__ A,
                                                  const ushort* __restrict__ Bt,
                                                  const float* __restrict__ emb_b,
                                                  const float* __restrict__ cls_tok,
                                                  float* __restrict__ x) {
    __shared__ ushort As[64 * 32];
    __shared__ ushort Bs[64 * 32];
    int tid = threadIdx.x;
    int lane = tid & 63;
    int w = __builtin_amdgcn_readfirstlane(tid >> 6);
    int quad = lane >> 4, l15 = lane & 15;
    int wr = (w >> 1) * 32, wc = (w & 1) * 32;
    int m0 = blockIdx.x * 64, n0 = blockIdx.y * 64;

    floatx4 acc[2][2];
    #pragma unroll
    for (int i = 0; i < 2; ++i)
        #pragma unroll
        for (int j = 0; j < 2; ++j) acc[i][j] = (floatx4)0.f;

    int lrow = lane >> 2;
    int lk = (lane & 3) * 8;
    const ushort* Ag = A + (size_t)(m0 + 16 * w + lrow) * F + lk;
    const ushort* Bg = Bt + (size_t)(n0 + 16 * w + lrow) * F + lk;
    ushort* AsW = &As[16 * w * 32];
    ushort* BsW = &Bs[16 * w * 32];
    int fa = l15 * 32 + quad * 8;

    for (int kt = 0; kt < F; kt += 32) {
        gload_lds16(Ag + kt, AsW);
        gload_lds16(Bg + kt, BsW);
        __syncthreads();
        short8 af[2], bf[2];
        #pragma unroll
        for (int i = 0; i < 2; ++i) af[i] = *(const short8*)&As[(wr + 16 * i) * 32 + fa];
        #pragma unroll
        for (int j = 0; j < 2; ++j) bf[j] = *(const short8*)&Bs[(wc + 16 * j) * 32 + fa];
        #pragma unroll
        for (int i = 0; i < 2; ++i)
            #pragma unroll
            for (int j = 0; j < 2; ++j)
                acc[i][j] = __builtin_amdgcn_mfma_f32_16x16x32_bf16(af[i], bf[j], acc[i][j], 0, 0, 0);
        __syncthreads();
    }

    const float LOG1E4 = 9.210340371976184f;
    int rbase = (lane >> 4) * 4;
    int cidx = lane & 15;
    #pragma unroll
    for (int j = 0; j < 2; ++j) {
        int gc = n0 + wc + 16 * j + cidx;
        float je = (float)(gc & ~1);
        float freq = expf(-(je / (float)D) * LOG1E4);
        float ebv = emb_b[gc];
        float clsv = cls_tok[gc];
        bool odd = (gc & 1);
        #pragma unroll
        for (int i = 0; i < 2; ++i) {
            int gr = m0 + wr + 16 * i + rbase;
            #pragma unroll
            for (int reg = 0; reg < 4; ++reg) {
                int row = gr + reg;
                int t = row & (T - 1);
                float ang = (float)t * freq;
                float pe = odd ? cosf(ang) : sinf(ang);
                float val = (t == 0) ? (clsv + pe) : (acc[i][j][reg] + ebv + pe);
                x[(size_t)row * D + gc] = val;
            }
        }
    }
}

// ---------------- layernorm -> bf16: one wave per row, shuffle-only ----------------
__global__ __launch_bounds__(256) void ln_kernel(const float* __restrict__ xin,
                                                 const float* __restrict__ g,
                                                 const float* __restrict__ bb,
                                                 ushort* __restrict__ out) {
    int lane = threadIdx.x & 63;
    int row = blockIdx.x * 4 + (threadIdx.x >> 6);
    const float* xr = xin + (size_t)row * D + lane * 8;
    float4 a0 = *(const float4*)xr;
    float4 a1 = *(const float4*)(xr + 4);
    float s = a0.x + a0.y + a0.z + a0.w + a1.x + a1.y + a1.z + a1.w;
    #pragma unroll
    for (int off = 1; off < 64; off <<= 1) s += __shfl_xor(s, off);
    float mean = s * (1.0f / (float)D);
    float d0 = a0.x - mean, d1 = a0.y - mean, d2 = a0.z - mean, d3 = a0.w - mean;
    float d4 = a1.x - mean, d5 = a1.y - mean, d6 = a1.z - mean, d7 = a1.w - mean;
    float sq = d0*d0 + d1*d1 + d2*d2 + d3*d3 + d4*d4 + d5*d5 + d6*d6 + d7*d7;
    #pragma unroll
    for (int off = 1; off < 64; off <<= 1) sq += __shfl_xor(sq, off);
    float rstd = rsqrtf(sq * (1.0f / (float)D) + EPS);
    const float* gp = g + lane * 8;
    const float* bp = bb + lane * 8;
    float4 g0 = *(const float4*)gp, g1 = *(const float4*)(gp + 4);
    float4 b0 = *(const float4*)bp, b1 = *(const float4*)(bp + 4);
    short8 o;
    o[0] = (short)f2bf(d0 * rstd * g0.x + b0.x);
    o[1] = (short)f2bf(d1 * rstd * g0.y + b0.y);
    o[2] = (short)f2bf(d2 * rstd * g0.z + b0.z);
    o[3] = (short)f2bf(d3 * rstd * g0.w + b0.w);
    o[4] = (short)f2bf(d4 * rstd * g1.x + b1.x);
    o[5] = (short)f2bf(d5 * rstd * g1.y + b1.y);
    o[6] = (short)f2bf(d6 * rstd * g1.z + b1.z);
    o[7] = (short)f2bf(d7 * rstd * g1.w + b1.w);
    *(short8*)(out + (size_t)row * D + lane * 8) = o;
}

// ---------------- fused: x += p0 (deferred W2 partial), then LN -> bf16 ----------------
__global__ __launch_bounds__(256) void ln_fuse_kernel(float* __restrict__ x,
                                                      const float* __restrict__ p0,
                                                      const float* __restrict__ g,
                                                      const float* __restrict__ bb,
                                                      ushort* __restrict__ out) {
    int lane = threadIdx.x & 63;
    int row = blockIdx.x * 4 + (threadIdx.x >> 6);
    size_t base = (size_t)row * D + lane * 8;
    float* xr = x + base;
    float4 a0 = *(const float4*)xr;
    float4 a1 = *(const float4*)(xr + 4);
    float4 q0 = *(const float4*)(p0 + base);
    float4 q1 = *(const float4*)(p0 + base + 4);
    a0.x += q0.x; a0.y += q0.y; a0.z += q0.z; a0.w += q0.w;
    a1.x += q1.x; a1.y += q1.y; a1.z += q1.z; a1.w += q1.w;
    *(float4*)xr = a0;
    *(float4*)(xr + 4) = a1;
    float s = a0.x + a0.y + a0.z + a0.w + a1.x + a1.y + a1.z + a1.w;
    #pragma unroll
    for (int off = 1; off < 64; off <<= 1) s += __shfl_xor(s, off);
    float mean = s * (1.0f / (float)D);
    float d0 = a0.x - mean, d1 = a0.y - mean, d2 = a0.z - mean, d3 = a0.w - mean;
    float d4 = a1.x - mean, d5 = a1.y - mean, d6 = a1.z - mean, d7 = a1.w - mean;
    float sq = d0*d0 + d1*d1 + d2*d2 + d3*d3 + d4*d4 + d5*d5 + d6*d6 + d7*d7;
    #pragma unroll
    for (int off = 1; off < 64; off <<= 1) sq += __shfl_xor(sq, off);
    float rstd = rsqrtf(sq * (1.0f / (float)D) + EPS);
    const float* gp = g + lane * 8;
    const float* bp = bb + lane * 8;
    float4 g0 = *(const float4*)gp, g1 = *(const float4*)(gp + 4);
    float4 b0 = *(const float4*)bp, b1 = *(const float4*)(bp + 4);
    short8 o;
    o[0] = (short)f2bf(d0 * rstd * g0.x + b0.x);
    o[1] = (short)f2bf(d1 * rstd * g0.y + b0.y);
    o[2] = (short)f2bf(d2 * rstd * g0.z + b0.z);
    o[3] = (short)f2bf(d3 * rstd * g0.w + b0.w);
    o[4] = (short)f2bf(d4 * rstd * g1.x + b1.x);
    o[5] = (short)f2bf(d5 * rstd * g1.y + b1.y);
    o[6] = (short)f2bf(d6 * rstd * g1.z + b1.z);
    o[7] = (short)f2bf(d7 * rstd * g1.w + b1.w);
    *(short8*)(out + (size_t)row * D + lane * 8) = o;
}

// ---------------- QKV: per-head MFMA GEMM ----------------
__global__ __launch_bounds__(256) void qkv_kernel(
        const ushort* __restrict__ hb,
        const ushort* __restrict__ WqT, const float* __restrict__ bq,
        const ushort* __restrict__ WkT, const float* __restrict__ bk,
        const ushort* __restrict__ WvT, const float* __restrict__ bv,
        ushort* __restrict__ qo, ushort* __restrict__ ko, ushort* __restrict__ vTo) {
    int m0 = blockIdx.x * 128;
    int hh = blockIdx.y;
    int tid = threadIdx.x;
    int lane = tid & 63;
    int w = __builtin_amdgcn_readfirstlane(tid >> 6);
    int quad = lane >> 4, l15 = lane & 15;

    short8 af[2][2];
    #pragma unroll
    for (int mt = 0; mt < 2; ++mt) {
        const ushort* ab = hb + (size_t)(m0 + w * 32 + mt * 16 + l15) * D + hh * DH + quad * 8;
        af[mt][0] = *(const short8*)(ab);
        af[mt][1] = *(const short8*)(ab + 32);
    }

    floatx4 acc[3][2][4];
    #pragma unroll
    for (int xo = 0; xo < 3; ++xo)
        #pragma unroll
        for (int mt = 0; mt < 2; ++mt)
            #pragma unroll
            for (int nt = 0; nt < 4; ++nt) acc[xo][mt][nt] = (floatx4)0.f;

    #pragma unroll
    for (int xo = 0; xo < 3; ++xo) {
        const ushort* WT = (xo == 0 ? WqT : xo == 1 ? WkT : WvT) + (size_t)hh * 4096;
        #pragma unroll
        for (int nt = 0; nt < 4; ++nt) {
            const ushort* wb = WT + (size_t)(nt * 16 + l15) * 64 + quad * 8;
            short8 bf0 = *(const short8*)(wb);
            short8 bf1 = *(const short8*)(wb + 32);
            #pragma unroll
            for (int mt = 0; mt < 2; ++mt) {
                acc[xo][mt][nt] = __builtin_amdgcn_mfma_f32_16x16x32_bf16(af[mt][0], bf0, acc[xo][mt][nt], 0, 0, 0);
                acc[xo][mt][nt] = __builtin_amdgcn_mfma_f32_16x16x32_bf16(af[mt][1], bf1, acc[xo][mt][nt], 0, 0, 0);
            }
        }
    }

    int bb = m0 >> 9;
    int bh = bb * H + hh;
    #pragma unroll
    for (int mt = 0; mt < 2; ++mt) {
        int trow = m0 + w * 32 + mt * 16 + quad * 4;
        int tt = trow & (T - 1);
        #pragma unroll
        for (int nt = 0; nt < 4; ++nt) {
            int col = nt * 16 + l15;
            float bqv = bq[hh * DH + col];
            float bkv = bk[hh * DH + col];
            float bvv = bv[hh * DH + col];
            #pragma unroll
            for (int reg = 0; reg < 4; ++reg) {
                qo[((size_t)bh * T + tt + reg) * DH + col] = f2bf(acc[0][mt][nt][reg] + bqv);
                ko[((size_t)bh * T + tt + reg) * DH + col] = f2bf(acc[1][mt][nt][reg] + bkv);
                vTo[((size_t)bh * DH + col) * T + tt + reg] = f2bf(acc[2][mt][nt][reg] + bvv);
            }
        }
    }
}

// ---------------- MFMA flash attention, max-free softmax + deferred normalization ----------------
#define PSTRIDE 88
__global__ __launch_bounds__(256) void attn_kernel(const ushort* __restrict__ q,
                                                   const ushort* __restrict__ k,
                                                   const ushort* __restrict__ vT,
                                                   float* __restrict__ x) {
    int bh = blockIdx.x;
    int qt = blockIdx.y;
    int b = bh >> 3, hh = bh & 7;
    int tid = threadIdx.x;
    int lane = tid & 63;
    int w = __builtin_amdgcn_readfirstlane(tid >> 6);   // 0..3
    int quad = lane >> 4, l15 = lane & 15;

    __shared__ __align__(16) ushort smem[22016];   // 44032 B
    ushort* Pw = smem + 16384 + w * (16 * PSTRIDE);

    const ushort* qbase = q + ((size_t)bh * T + qt * 64 + w * 16 + l15) * DH + quad * 8;
    short8 Qf0 = *(const short8*)(qbase);
    short8 Qf1 = *(const short8*)(qbase + 32);

    const ushort* kbase = k + (size_t)bh * T * DH;
    const ushort* vbase = vT + (size_t)bh * DH * T;

    int srow = lane >> 2;
    int scol = (lane & 3) * 8;
    const ushort* kg = kbase + (size_t)(w * 16 + srow) * DH + scol;
    const ushort* vg = vbase + (size_t)(w * 16 + srow) * T + scol;
    ushort* ldsK = smem + w * 16 * 32;
    ushort* ldsV = smem + 8192 + w * 16 * 32;

    float l_i[4] = {0.f, 0.f, 0.f, 0.f};
    floatx4 O[4];
    #pragma unroll
    for (int j = 0; j < 4; ++j) O[j] = (floatx4)0.f;

    gload_lds16(kg, ldsK);
    gload_lds16(kg + 32, ldsK + 2048);
    gload_lds16(vg, ldsV);
    gload_lds16(vg + 32, ldsV + 2048);
    __syncthreads();

    for (int kt = 0; kt < T / 64; ++kt) {
        int cur = kt & 1;
        if (kt < T / 64 - 1) {
            int nb = cur ^ 1;
            const ushort* kgn = kg + (size_t)(kt + 1) * 64 * DH;
            const ushort* vgn = vg + (kt + 1) * 64;
            gload_lds16(kgn, ldsK + nb * 4096);
            gload_lds16(kgn + 32, ldsK + nb * 4096 + 2048);
            gload_lds16(vgn, ldsV + nb * 4096);
            gload_lds16(vgn + 32, ldsV + nb * 4096 + 2048);
        }
        const ushort* Kc = smem + cur * 4096;
        const ushort* Vc = smem + 8192 + cur * 4096;

        floatx4 sc[4];
        #pragma unroll
        for (int j = 0; j < 4; ++j) {
            int ro = (j * 16 + l15) * 32 + quad * 8;
            short8 kf0 = *(const short8*)&Kc[ro];
            short8 kf1 = *(const short8*)&Kc[2048 + ro];
            floatx4 s4 = (floatx4)0.f;
            s4 = __builtin_amdgcn_mfma_f32_16x16x32_bf16(Qf0, kf0, s4, 0, 0, 0);
            s4 = __builtin_amdgcn_mfma_f32_16x16x32_bf16(Qf1, kf1, s4, 0, 0, 0);
            sc[j] = s4;
        }
        #pragma unroll
        for (int j = 0; j < 4; ++j) {
            #pragma unroll
            for (int r = 0; r < 4; ++r) {
                float p = __expf(sc[j][r] * 0.125f);
                ushort pb = f2bf(p);
                union { unsigned u; float f; } cv; cv.u = ((unsigned)pb) << 16;
                l_i[r] += cv.f;
                Pw[(quad * 4 + r) * PSTRIDE + j * 16 + l15] = pb;
            }
        }

        short8 af0 = *(const short8*)&Pw[l15 * PSTRIDE + quad * 8];
        short8 af1 = *(const short8*)&Pw[l15 * PSTRIDE + 32 + quad * 8];
        #pragma unroll
        for (int j = 0; j < 4; ++j) {
            int ro = (j * 16 + l15) * 32 + quad * 8;
            short8 vf0 = *(const short8*)&Vc[ro];
            short8 vf1 = *(const short8*)&Vc[2048 + ro];
            O[j] = __builtin_amdgcn_mfma_f32_16x16x32_bf16(af0, vf0, O[j], 0, 0, 0);
            O[j] = __builtin_amdgcn_mfma_f32_16x16x32_bf16(af1, vf1, O[j], 0, 0, 0);
        }
        __syncthreads();
    }

    #pragma unroll
    for (int r = 0; r < 4; ++r) {
        l_i[r] += __shfl_xor(l_i[r], 1);
        l_i[r] += __shfl_xor(l_i[r], 2);
        l_i[r] += __shfl_xor(l_i[r], 4);
        l_i[r] += __shfl_xor(l_i[r], 8);
    }

    float* Ow = (float*)smem + w * 16 * 68;
    #pragma unroll
    for (int r = 0; r < 4; ++r) {
        float rl = 1.0f / l_i[r];
        #pragma unroll
        for (int j = 0; j < 4; ++j)
            Ow[(quad * 4 + r) * 68 + j * 16 + l15] = O[j][r] * rl;
    }
    __syncthreads();
    int r4 = lane >> 4;
    int c16 = lane & 15;
    #pragma unroll
    for (int i = 0; i < 4; ++i) {
        int lrow = i * 4 + r4;
        float4 o = *(const float4*)&Ow[lrow * 68 + c16 * 4];
        int grow = qt * 64 + w * 16 + lrow;
        float* xp = &x[((size_t)(b * T) + grow) * D + hh * DH + c16 * 4];
        float4 xv = *(const float4*)xp;
        xv.x += o.x; xv.y += o.y; xv.z += o.z; xv.w += o.w;
        *(float4*)xp = xv;
    }
}

// ---------------- gemm1: C(bf16) = gelu(A@Bt^T + bias), tile 128x64, full K ----------------
// Retiled from 128x128: LDS 24KB (6 blocks/CU), acc 32 regs, grid 2048 blocks (8/CU)
// -> raises resident waves so staging vmcnt drains are hidden (was Occupancy 16%).
__global__ __launch_bounds__(256) void mfma_gemm_gelu(const ushort* __restrict__ A,
                                                      const ushort* __restrict__ Bt,
                                                      const float* __restrict__ bias,
                                                      ushort* __restrict__ C,
                                                      int M, int N, int K) {
    __shared__ ushort As0[128 * 32];
    __shared__ ushort As1[128 * 32];
    __shared__ ushort Bs0[64 * 32];
    __shared__ ushort Bs1[64 * 32];
    int tid = threadIdx.x;
    int lane = tid & 63;
    int w = __builtin_amdgcn_readfirstlane(tid >> 6);
    int wr = (w >> 1) * 64, wc = (w & 1) * 32;
    int m0 = blockIdx.x * 128, n0 = blockIdx.y * 64;

    floatx4 acc[4][2];
    #pragma unroll
    for (int i = 0; i < 4; ++i)
        #pragma unroll
        for (int j = 0; j < 2; ++j) acc[i][j] = (floatx4)0.f;

    int lrow = lane >> 2;
    int lk = (lane & 3) * 8;
    const ushort* Ag = A + (size_t)(m0 + 32 * w + lrow) * K + lk;
    const ushort* Bg = Bt + (size_t)(n0 + 16 * w + lrow) * K + lk;
    ushort* As0W = &As0[(32 * w) * 32];
    ushort* As1W = &As1[(32 * w) * 32];
    ushort* Bs0W = &Bs0[(16 * w) * 32];
    ushort* Bs1W = &Bs1[(16 * w) * 32];
    int fa = (lane & 15) * 32 + (lane >> 4) * 8;

    for (int kt = 0; kt < K; kt += 64) {
        gload_lds16(Ag + kt, As0W);
        gload_lds16(Ag + kt + (size_t)16 * K, As0W + 16 * 32);
        gload_lds16(Ag + kt + 32, As1W);
        gload_lds16(Ag + kt + 32 + (size_t)16 * K, As1W + 16 * 32);
        gload_lds16(Bg + kt, Bs0W);
        gload_lds16(Bg + kt + 32, Bs1W);
        __syncthreads();
        short8 af0[4], af1[4], bf0[2], bf1[2];
        #pragma unroll
        for (int i = 0; i < 4; ++i) {
            af0[i] = *(const short8*)&As0[(wr + 16 * i) * 32 + fa];
            af1[i] = *(const short8*)&As1[(wr + 16 * i) * 32 + fa];
        }
        #pragma unroll
        for (int j = 0; j < 2; ++j) {
            bf0[j] = *(const short8*)&Bs0[(wc + 16 * j) * 32 + fa];
            bf1[j] = *(const short8*)&Bs1[(wc + 16 * j) * 32 + fa];
        }
        #pragma unroll
        for (int i = 0; i < 4; ++i)
            #pragma unroll
            for (int j = 0; j < 2; ++j) {
                acc[i][j] = __builtin_amdgcn_mfma_f32_16x16x32_bf16(af0[i], bf0[j], acc[i][j], 0, 0, 0);
                acc[i][j] = __builtin_amdgcn_mfma_f32_16x16x32_bf16(af1[i], bf1[j], acc[i][j], 0, 0, 0);
            }
        __syncthreads();
    }

    int rbase = (lane >> 4) * 4;
    int cidx = lane & 15;
    #pragma unroll
    for (int i = 0; i < 4; ++i) {
        #pragma unroll
        for (int j = 0; j < 2; ++j) {
            int gc = n0 + wc + 16 * j + cidx;
            float bv = bias[gc];
            int gr = m0 + wr + 16 * i + rbase;
            #pragma unroll
            for (int reg = 0; reg < 4; ++reg) {
                float val = fast_gelu(acc[i][j][reg] + bv);
                C[(size_t)(gr + reg) * N + gc] = f2bf(val);
            }
        }
    }
}

// ---------------- gemm2: P(fp32) = A@Bt^T + bias, tile 128x64, full K ----------------
__global__ __launch_bounds__(256) void mfma_gemm_p(const ushort* __restrict__ A,
                                                   const ushort* __restrict__ Bt,
                                                   const float* __restrict__ bias,
                                                   float* __restrict__ C,
                                                   int M, int N, int K) {
    __shared__ ushort As0[128 * 32];
    __shared__ ushort As1[128 * 32];
    __shared__ ushort Bs0[64 * 32];
    __shared__ ushort Bs1[64 * 32];
    int tid = threadIdx.x;
    int lane = tid & 63;
    int w = __builtin_amdgcn_readfirstlane(tid >> 6);
    int wr = (w >> 1) * 64, wc = (w & 1) * 32;
    int m0 = blockIdx.x * 128, n0 = blockIdx.y * 64;

    floatx4 acc[4][2];
    #pragma unroll
    for (int i = 0; i < 4; ++i)
        #pragma unroll
        for (int j = 0; j < 2; ++j) acc[i][j] = (floatx4)0.f;

    int lrow = lane >> 2;
    int lk = (lane & 3) * 8;
    const ushort* Ag = A + (size_t)(m0 + 32 * w + lrow) * K + lk;
    const ushort* Bg = Bt + (size_t)(n0 + 16 * w + lrow) * K + lk;
    ushort* As0W = &As0[(32 * w) * 32];
    ushort* As1W = &As1[(32 * w) * 32];
    ushort* Bs0W = &Bs0[(16 * w) * 32];
    ushort* Bs1W = &Bs1[(16 * w) * 32];
    int fa = (lane & 15) * 32 + (lane >> 4) * 8;

    for (int kt = 0; kt < K; kt += 64) {
        gload_lds16(Ag + kt, As0W);
        gload_lds16(Ag + kt + (size_t)16 * K, As0W + 16 * 32);
        gload_lds16(Ag + kt + 32, As1W);
        gload_lds16(Ag + kt + 32 + (size_t)16 * K, As1W + 16 * 32);
        gload_lds16(Bg + kt, Bs0W);
        gload_lds16(Bg + kt + 32, Bs1W);
        __syncthreads();
        short8 af0[4], af1[4], bf0[2], bf1[2];
        #pragma unroll
        for (int i = 0; i < 4; ++i) {
            af0[i] = *(const short8*)&As0[(wr + 16 * i) * 32 + fa];
            af1[i] = *(const short8*)&As1[(wr + 16 * i) * 32 + fa];
        }
        #pragma unroll
        for (int j = 0; j < 2; ++j) {
            bf0[j] = *(const short8*)&Bs0[(wc + 16 * j) * 32 + fa];
            bf1[j] = *(const short8*)&Bs1[(wc + 16 * j) * 32 + fa];
        }
        #pragma unroll
        for (int i = 0; i < 4; ++i)
            #pragma unroll
            for (int j = 0; j < 2; ++j) {
                acc[i][j] = __builtin_amdgcn_mfma_f32_16x16x32_bf16(af0[i], bf0[j], acc[i][j], 0, 0, 0);
                acc[i][j] = __builtin_amdgcn_mfma_f32_16x16x32_bf16(af1[i], bf1[j], acc[i][j], 0, 0, 0);
            }
        __syncthreads();
    }

    int rbase = (lane >> 4) * 4;
    int cidx = lane & 15;
    #pragma unroll
    for (int i = 0; i < 4; ++i) {
        #pragma unroll
        for (int j = 0; j < 2; ++j) {
            int gc = n0 + wc + 16 * j + cidx;
            float bv = bias[gc];
            int gr = m0 + wr + 16 * i + rbase;
            #pragma unroll
            for (int reg = 0; reg < 4; ++reg) {
                C[(size_t)(gr + reg) * N + gc] = acc[i][j][reg] + bv;
            }
        }
    }
}

// ---------------- head: out[b] = sigmoid((x[b,0]+p0[b,0]) . head_W + head_b) ----------------
__global__ void head_kernel(const float* __restrict__ x,
                            const float* __restrict__ p0,
                            const float* __restrict__ hw,
                            const float* __restrict__ hb,
                            float* __restrict__ out) {
    int b = blockIdx.x;
    int tid = threadIdx.x; // 512
    size_t idx = (size_t)b * T * D + tid;
    float s = (x[idx] + p0[idx]) * hw[tid];
    #pragma unroll
    for (int off = 32; off > 0; off >>= 1) s += __shfl_down(s, off, 64);
    __shared__ float red[8];
    if ((tid & 63) == 0) red[tid >> 6] = s;
    __syncthreads();
    if (tid == 0) {
        float t = 0.f;
        #pragma unroll
        for (int i = 0; i < 8; ++i) t += red[i];
        out[b] = 1.0f / (1.0f + __expf(-(t + hb[0])));
    }
}

extern "C" void kernel_launch(void* const* d_in, const int* in_sizes, int n_in,
                              void* d_out, int out_size, void* d_ws, size_t ws_size,
                              hipStream_t stream) {
    const float* src     = (const float*)d_in[0];
    const float* emb_W   = (const float*)d_in[1];
    const float* emb_b   = (const float*)d_in[2];
    const float* cls_tok = (const float*)d_in[3];
    const float* ln1_g   = (const float*)d_in[4];
    const float* ln1_b   = (const float*)d_in[5];
    const float* Wq      = (const float*)d_in[6];
    const float* bq      = (const float*)d_in[7];
    const float* Wk      = (const float*)d_in[8];
    const float* bk      = (const float*)d_in[9];
    const float* Wv      = (const float*)d_in[10];
    const float* bv      = (const float*)d_in[11];
    const float* ln2_g   = (const float*)d_in[12];
    const float* ln2_b   = (const float*)d_in[13];
    const float* W1      = (const float*)d_in[14];
    const float* b1      = (const float*)d_in[15];
    const float* W2      = (const float*)d_in[16];
    const float* b2      = (const float*)d_in[17];
    const float* head_W  = (const float*)d_in[18];
    const float* head_b  = (const float*)d_in[19];

    const size_t NTOK = (size_t)B * T;          // 8192
    char* wsb = (char*)d_ws;
    float*  x    = (float*)wsb;      wsb += NTOK * D * 4;
    float*  p0   = (float*)wsb;      wsb += NTOK * D * 4;      // single W2 partial (16MB)
    ushort* hbuf = (ushort*)wsb;     wsb += NTOK * D * 2;
    ushort* q    = (ushort*)wsb;     wsb += NTOK * D * 2;
    ushort* k    = (ushort*)wsb;     wsb += NTOK * D * 2;
    ushort* vT   = (ushort*)wsb;     wsb += NTOK * D * 2;
    ushort* u    = (ushort*)wsb;     wsb += NTOK * MLPD * 2;
    ushort* W1t  = (ushort*)wsb;     wsb += (size_t)NB * D * MLPD * 2;
    ushort* W2t  = (ushort*)wsb;     wsb += (size_t)NB * D * MLPD * 2;
    ushort* WqT  = (ushort*)wsb;     wsb += (size_t)NB * H * DH * DH * 2;
    ushort* WkT  = (ushort*)wsb;     wsb += (size_t)NB * H * DH * DH * 2;
    ushort* WvT  = (ushort*)wsb;     wsb += (size_t)NB * H * DH * DH * 2;
    ushort* srcb = (ushort*)wsb;     wsb += NTOK * F * 2;
    ushort* embWt= (ushort*)wsb;     wsb += (size_t)F * D * 2;

    // weight / input prep (every launch)
    wtrans_kernel<<<dim3(D / 32, MLPD / 32, NB), 256, 0, stream>>>(W1, W1t, D, MLPD);
    wtrans_kernel<<<dim3(MLPD / 32, D / 32, NB), 256, 0, stream>>>(W2, W2t, MLPD, D);
    wtransq_kernel<<<dim3(NB * H, 3), 256, 0, stream>>>(Wq, Wk, Wv, WqT, WkT, WvT);
    wtrans_kernel<<<dim3(F / 32, D / 32, 1), 256, 0, stream>>>(emb_W, embWt, F, D);
    castsrc_kernel<<<B * T, F, 0, stream>>>(src, srcb);

    embed_gemm<<<dim3(B * T / 64, D / 64), 256, 0, stream>>>(srcb, embWt, emb_b, cls_tok, x);

    for (int i = 0; i < NB; ++i) {
        if (i == 0)
            ln_kernel<<<B * T / 4, 256, 0, stream>>>(x, ln1_g, ln1_b, hbuf);
        else
            ln_fuse_kernel<<<B * T / 4, 256, 0, stream>>>(x, p0,
                ln1_g + i * D, ln1_b + i * D, hbuf);
        qkv_kernel<<<dim3(B * T / 128, H), 256, 0, stream>>>(hbuf,
            WqT + (size_t)i * H * DH * DH, bq + (size_t)i * H * DH,
            WkT + (size_t)i * H * DH * DH, bk + (size_t)i * H * DH,
            WvT + (size_t)i * H * DH * DH, bv + (size_t)i * H * DH,
            q, k, vT);
        attn_kernel<<<dim3(B * H, T / 64), 256, 0, stream>>>(q, k, vT, x);
        ln_kernel<<<B * T / 4, 256, 0, stream>>>(x, ln2_g + i * D, ln2_b + i * D, hbuf);
        mfma_gemm_gelu<<<dim3(B * T / 128, MLPD / 64), 256, 0, stream>>>(
            hbuf, W1t + (size_t)i * D * MLPD, b1 + (size_t)i * MLPD, u, B * T, MLPD, D);
        mfma_gemm_p<<<dim3(B * T / 128, D / 64), 256, 0, stream>>>(
            u, W2t + (size_t)i * MLPD * D, b2 + (size_t)i * D, p0, B * T, D, MLPD);
    }

    head_kernel<<<B, 512, 0, stream>>>(x, p0, head_W, head_b, (float*)d_out);
}